// Round 9
// baseline (341.699 us; speedup 1.0000x reference)
//
#include <hip/hip_runtime.h>

#define N 2048
#define LEV 256
#define KS 16

typedef __attribute__((ext_vector_type(8))) short bfx8;
typedef __attribute__((ext_vector_type(4))) float fx4;
typedef unsigned short u16;
typedef unsigned int u32;

static const size_t NN = (size_t)N * N;

__device__ inline u16 bf16_rne(float f) {
    u32 u = __builtin_bit_cast(u32, f);
    u32 r = (u + 0x7FFFu + ((u >> 16) & 1u)) >> 16;
    return (u16)r;
}
__device__ inline float bf16_f(u16 h) {
    u32 u = ((u32)h) << 16;
    return __builtin_bit_cast(float, u);
}

// async global->LDS, 16B per lane. LDS dest = wave-uniform base + lane*16.
#define GLDS16(gp, lp) __builtin_amdgcn_global_load_lds( \
    (const __attribute__((address_space(1))) void*)(uintptr_t)(gp), \
    (__attribute__((address_space(3))) void*)(u32)(uintptr_t)(lp), 16, 0, 0)

// sum over the 4 lanes of each quad (lane^1 then lane^2), VALU-only via DPP.
__device__ inline float qadd(float x) {
#if __has_builtin(__builtin_amdgcn_mov_dpp)
    int a = __builtin_amdgcn_mov_dpp(__builtin_bit_cast(int, x), 0xB1, 0xF, 0xF, true);
    float y = x + __builtin_bit_cast(float, a);
    int b = __builtin_amdgcn_mov_dpp(__builtin_bit_cast(int, y), 0x4E, 0xF, 0xF, true);
    return y + __builtin_bit_cast(float, b);
#else
    float y = x + __shfl_xor(x, 1);
    return y + __shfl_xor(y, 2);
#endif
}

// ---------------------------------------------------------------------------
// build RT = (U_{L-1}...U_0)^T, ONE column per wave (R7 structure: 8KB LDS,
// grid 2048 -> ~8 waves/CU) + TWO-level-deep prefetch so the O/sel L2
// latency (~200-400cy) is covered by ~2 compute blocks (~440cy).
// Single wave -> DS program order, no barriers.
// ---------------------------------------------------------------------------
__global__ __launch_bounds__(64)
void build_right_k(const float* __restrict__ O_all, const int* __restrict__ sel,
                   float* __restrict__ RT) {
    __shared__ float x[2048];
    const int lane = threadIdx.x;
    const int i    = lane >> 2;     // row 0..15
    const int kg   = lane & 3;      // k-quarter 0..3
    const int col  = blockIdx.x;

    const float4 z = make_float4(0.f, 0.f, 0.f, 0.f);
    #pragma unroll
    for (int q = 0; q < 8; ++q) *(float4*)&x[q * 256 + lane * 4] = z;
    if (lane == 0) x[col] = 1.0f;   // e_col; in-order DS, same wave

    const float* obase = O_all + i * KS + kg * 4;
    const int*   gbase = sel + kg * 4;

#define CMP(f, g, wv) { \
    float p = f.x * x[g.x] + f.y * x[g.y] + f.z * x[g.z] + f.w * x[g.w]; \
    p = qadd(p); \
    if (kg == 0) x[wv] = p; }

    float4 f0 = *(const float4*)(obase);
    int4   g0 = *(const int4*)(gbase);
    int    w0 = sel[i];
    float4 f1 = *(const float4*)(obase + 256);
    int4   g1 = *(const int4*)(gbase + KS);
    int    w1 = sel[KS + i];

    for (int l = 0; l < LEV; l += 2) {
        float4 f2, f3; int4 g2, g3; int w2, w3;
        if (l + 2 < LEV) {          // issue both prefetches up front
            f2 = *(const float4*)(obase + (size_t)(l + 2) * 256);
            g2 = *(const int4*)(gbase + (l + 2) * KS);
            w2 = sel[(l + 2) * KS + i];
            f3 = *(const float4*)(obase + (size_t)(l + 3) * 256);
            g3 = *(const int4*)(gbase + (l + 3) * KS);
            w3 = sel[(l + 3) * KS + i];
        } else { f2 = f0; g2 = g0; w2 = w0; f3 = f1; g3 = g1; w3 = w1; }

        CMP(f0, g0, w0)             // level l   (~220cy of LDS+VALU chain)
        CMP(f1, g1, w1)             // level l+1
        f0 = f2; g0 = g2; w0 = w2;  // vmcnt wait lands here, ~2 levels after issue
        f1 = f3; g1 = g3; w1 = w3;
    }
#undef CMP

    #pragma unroll
    for (int q = 0; q < 8; ++q)
        *(float4*)&RT[(size_t)col * N + q * 256 + lane * 4] =
            *(const float4*)&x[q * 256 + lane * 4];
}

// ---------------------------------------------------------------------------
// split fp32 matrix -> bf16 hi/lo planes (streaming)
// ---------------------------------------------------------------------------
__global__ __launch_bounds__(256)
void split_plain_k(const float* __restrict__ src, u16* __restrict__ dh) {
    u16* dl = dh + NN;
    size_t p = ((size_t)blockIdx.x * 256 + threadIdx.x) * 8;
    float4 v0 = *(const float4*)(src + p);
    float4 v1 = *(const float4*)(src + p + 4);
    float vv[8] = {v0.x, v0.y, v0.z, v0.w, v1.x, v1.y, v1.z, v1.w};
    bfx8 hs, ls;
    #pragma unroll
    for (int i = 0; i < 8; ++i) {
        u16 h = bf16_rne(vv[i]);
        hs[i] = (short)h;
        ls[i] = (short)bf16_rne(vv[i] - bf16_f(h));
    }
    *(bfx8*)(dh + p) = hs;
    *(bfx8*)(dl + p) = ls;
}

// ---------------------------------------------------------------------------
// From RT (= R^T row-major): R2 = split(R), RT2 = split(RT), R fp32 row-major.
// ---------------------------------------------------------------------------
__global__ __launch_bounds__(256)
void split_rt_k(const float* __restrict__ RT, u16* __restrict__ r2h,
                u16* __restrict__ rth, float* __restrict__ Rrm) {
    __shared__ float t[64][65];
    u16* r2l = r2h + NN;
    u16* rtl = rth + NN;
    const int r0 = (blockIdx.x >> 5) * 64, c0 = (blockIdx.x & 31) * 64;
    #pragma unroll
    for (int i = 0; i < 16; ++i) {
        int q = i * 256 + threadIdx.x;
        int rr = q >> 6, cc = q & 63;
        t[rr][cc] = RT[(size_t)(r0 + rr) * N + c0 + cc];
    }
    __syncthreads();
    #pragma unroll
    for (int i = 0; i < 16; ++i) {
        int q = i * 256 + threadIdx.x;
        int rr = q >> 6, cc = q & 63;
        float v = t[rr][cc];                        // RT[r0+rr][c0+cc]
        u16 h = bf16_rne(v);
        size_t po = (size_t)(r0 + rr) * N + c0 + cc;
        rth[po] = h;                                // split(RT)
        rtl[po] = bf16_rne(v - bf16_f(h));
        float w = t[cc][rr];                        // = R[c0+rr][r0+cc]
        u16 h2 = bf16_rne(w);
        size_t pt = (size_t)(c0 + rr) * N + r0 + cc;
        r2h[pt] = h2;                               // split(R)
        r2l[pt] = bf16_rne(w - bf16_f(h2));
        Rrm[pt] = w;                                // R fp32 (output slot)
    }
}

// ---------------------------------------------------------------------------
// D fp32 = hi + lo
// ---------------------------------------------------------------------------
__global__ __launch_bounds__(256)
void unsplit_k(const u16* __restrict__ hi, float* __restrict__ dst) {
    const u16* lo = hi + NN;
    size_t p = ((size_t)blockIdx.x * 256 + threadIdx.x) * 8;
    bfx8 hs = *(const bfx8*)(hi + p);
    bfx8 ls = *(const bfx8*)(lo + p);
    float4 o0, o1;
    o0.x = bf16_f((u16)hs[0]) + bf16_f((u16)ls[0]);
    o0.y = bf16_f((u16)hs[1]) + bf16_f((u16)ls[1]);
    o0.z = bf16_f((u16)hs[2]) + bf16_f((u16)ls[2]);
    o0.w = bf16_f((u16)hs[3]) + bf16_f((u16)ls[3]);
    o1.x = bf16_f((u16)hs[4]) + bf16_f((u16)ls[4]);
    o1.y = bf16_f((u16)hs[5]) + bf16_f((u16)ls[5]);
    o1.z = bf16_f((u16)hs[6]) + bf16_f((u16)ls[6]);
    o1.w = bf16_f((u16)hs[7]) + bf16_f((u16)ls[7]);
    *(float4*)(dst + p)     = o0;
    *(float4*)(dst + p + 4) = o1;
}

// ---------------------------------------------------------------------------
// C = X * Y^T via 3-term bf16 split MFMA.
// global_load_lds double-buffer, both-sides XOR swizzle.
// SYMOUT=0: 128x128 tile, grid 256.
// SYMOUT=1: C symmetric. 128x64 tiles, 272 upper-tri blocks (bx>=2*by) ->
//   all CUs busy. Direct stores predicated to gj>=gi (single writer);
//   strict-lower mirror via LDS bounce.
// ---------------------------------------------------------------------------
template<int MASKED, int OMODE, int SYMOUT>
__global__ __launch_bounds__(256)
void gemm_bf3(const u16* __restrict__ Xp, const u16* __restrict__ Yp,
              float* __restrict__ Cf, u16* __restrict__ Cs,
              const int* __restrict__ wav, int Lw) {
    constexpr int BN   = SYMOUT ? 64 : 128;     // col-tile
    constexpr int NF   = BN / 32;               // n-frags per wave
    constexpr int PXu  = 8192;                  // u16 per X plane (128x64)
    constexpr int PYu  = BN * 64;               // u16 per Y plane
    constexpr int BUFB = (2 * PXu + 2 * PYu) * 2;  // bytes per buffer
    constexpr int XLB  = PXu * 2;               // Xl byte offset in buffer
    constexpr int YHB  = 2 * PXu * 2;           // Yh
    constexpr int YLB  = (2 * PXu + PYu) * 2;   // Yl
    __shared__ __align__(16) u16 sm[2 * (2 * PXu + 2 * PYu)];
    __shared__ float rowf[128], colf[128];

    const int tid = threadIdx.x;
    int bx, by;
    if (SYMOUT) {
        // 272 blocks = 8 XCD chunks of 34 (bijective)
        int swz = (blockIdx.x & 7) * 34 + (blockIdx.x >> 3);
        int t = swz; by = 0;
        #pragma unroll 1
        while (t >= 32 - 2 * by) { t -= 32 - 2 * by; ++by; }
        bx = 2 * by + t;                        // col tile index (64-wide)
    } else {
        const int swz = ((blockIdx.x & 7) << 5) | (blockIdx.x >> 3);
        bx = swz & 15;
        by = swz >> 4;
    }
    const int i0 = by * 128, j0 = bx * BN;
    const int lane = tid & 63, w = tid >> 6;
    const int wm = (w >> 1) * 64, wn = (w & 1) * (BN / 2);
    const int fr = lane & 15;

    if (MASKED) {
        if (tid < 128) rowf[tid] = 1.0f;
        if (tid >= 128 && tid < 128 + BN) colf[tid - 128] = 1.0f;
        __syncthreads();
        for (int t = tid; t < Lw; t += 256) {
            int wv = wav[t];
            int dr = wv - i0; if (0 <= dr && dr < 128) rowf[dr] = 0.0f;
            int dc = wv - j0; if (0 <= dc && dc < BN) colf[dc] = 0.0f;
        }
    }

    fx4 acc[4][NF];
    #pragma unroll
    for (int m = 0; m < 4; ++m)
        #pragma unroll
        for (int n = 0; n < NF; ++n)
            acc[m][n] = (fx4)0.0f;

    const u16* Xh = Xp; const u16* Xl = Xp + NN;
    const u16* Yh = Yp; const u16* Yl = Yp + NN;

    const int rl   = lane >> 3;
    const int gcol = ((lane & 7) ^ rl) << 3;
    const int wq   = w * 1024;

    #define STAGE(buf, kt) { \
        const int k0s = (kt) * 64; \
        char* bb = (char*)sm + (buf) * BUFB + wq; \
        _Pragma("unroll") \
        for (int q = 0; q < 4; ++q) { \
            const int row = q * 32 + w * 8 + rl; \
            const size_t xo = (size_t)(i0 + row) * N + k0s + gcol; \
            GLDS16(Xh + xo, bb + q * 4096); \
            GLDS16(Xl + xo, bb + XLB + q * 4096); \
        } \
        _Pragma("unroll") \
        for (int q = 0; q < BN / 32; ++q) { \
            const int row = q * 32 + w * 8 + rl; \
            const size_t yo = (size_t)(j0 + row) * N + k0s + gcol; \
            GLDS16(Yh + yo, bb + YHB + q * 4096); \
            GLDS16(Yl + yo, bb + YLB + q * 4096); \
        } }

    const int kq  = (lane >> 4) << 4;
    const int frx = (fr & 7) << 4;

    #define COMPUTE(buf) { \
        const char* base = (const char*)sm + (buf) * BUFB; \
        _Pragma("unroll") \
        for (int s = 0; s < 2; ++s) { \
            const int cb = s * 64 + kq; \
            bfx8 ah[4], al[4]; \
            _Pragma("unroll") \
            for (int m = 0; m < 4; ++m) { \
                const int off = (wm + m * 16 + fr) * 128 + (cb ^ frx); \
                ah[m] = *(const bfx8*)(base + off); \
                al[m] = *(const bfx8*)(base + XLB + off); \
            } \
            _Pragma("unroll") \
            for (int n = 0; n < NF; ++n) { \
                const int off = (wn + n * 16 + fr) * 128 + (cb ^ frx); \
                bfx8 bh = *(const bfx8*)(base + YHB + off); \
                bfx8 bl = *(const bfx8*)(base + YLB + off); \
                _Pragma("unroll") \
                for (int m = 0; m < 4; ++m) { \
                    acc[m][n] = __builtin_amdgcn_mfma_f32_16x16x32_bf16(ah[m], bh, acc[m][n], 0, 0, 0); \
                    acc[m][n] = __builtin_amdgcn_mfma_f32_16x16x32_bf16(ah[m], bl, acc[m][n], 0, 0, 0); \
                    acc[m][n] = __builtin_amdgcn_mfma_f32_16x16x32_bf16(al[m], bh, acc[m][n], 0, 0, 0); \
                } \
            } \
        } }

    constexpr int NT = N / 64;
    STAGE(0, 0)
    __syncthreads();
    for (int kt = 0; kt < NT; ++kt) {
        const int cur = kt & 1;
        if (kt + 1 < NT) STAGE(cur ^ 1, kt + 1)
        COMPUTE(cur)
        __syncthreads();
    }

    // ---- epilogue 1: direct fragment stores (SYM: only gj >= gi) ----
    float* Ct = (float*)sm;                     // [128][BN] stride 65 (SYM)
    const int crow0 = (lane >> 4) * 4;
    #pragma unroll
    for (int m = 0; m < 4; ++m) {
        #pragma unroll
        for (int n = 0; n < NF; ++n) {
            #pragma unroll
            for (int r = 0; r < 4; ++r) {
                const int li = wm + m * 16 + crow0 + r;
                const int lj = wn + n * 16 + fr;
                float v = acc[m][n][r];
                if (MASKED) {
                    if (i0 + li != j0 + lj) v *= rowf[li] * colf[lj];
                }
                if (SYMOUT) Ct[li * 65 + lj] = v;
                const size_t off = (size_t)(i0 + li) * N + j0 + lj;
                if (!SYMOUT || (j0 + lj >= i0 + li)) {
                    if (OMODE == 0) {
                        Cf[off] = v;
                    } else {
                        u16 h = bf16_rne(v);
                        Cs[off]      = h;
                        Cs[NN + off] = bf16_rne(v - bf16_f(h));
                    }
                }
            }
        }
    }

    // ---- epilogue 2 (SYM): strict-lower mirror via LDS bounce ----
    if (SYMOUT) {
        __syncthreads();
        const int rr  = tid >> 2;               // mirror row j0+rr (0..63)
        const int cc0 = (tid & 3) * 32;         // mirror cols i0+cc0..+31
        const int thr = j0 + rr - i0;           // write cc < thr (strict lower target)
        if (OMODE == 0) {
            #pragma unroll
            for (int t4 = 0; t4 < 8; ++t4) {
                const int cc = cc0 + t4 * 4;
                const size_t off = (size_t)(j0 + rr) * N + i0 + cc;
                if (cc + 4 <= thr) {
                    *(float4*)(Cf + off) = make_float4(
                        Ct[(cc + 0) * 65 + rr], Ct[(cc + 1) * 65 + rr],
                        Ct[(cc + 2) * 65 + rr], Ct[(cc + 3) * 65 + rr]);
                } else if (cc < thr) {
                    #pragma unroll
                    for (int e = 0; e < 4; ++e)
                        if (cc + e < thr) Cf[off + e] = Ct[(cc + e) * 65 + rr];
                }
            }
        } else {
            #pragma unroll
            for (int t8 = 0; t8 < 4; ++t8) {
                const int cc = cc0 + t8 * 8;
                const size_t off = (size_t)(j0 + rr) * N + i0 + cc;
                if (cc + 8 <= thr) {
                    bfx8 hs, ls;
                    #pragma unroll
                    for (int e = 0; e < 8; ++e) {
                        float v = Ct[(cc + e) * 65 + rr];
                        u16 h = bf16_rne(v);
                        hs[e] = (short)h;
                        ls[e] = (short)bf16_rne(v - bf16_f(h));
                    }
                    *(bfx8*)(Cs + off)      = hs;
                    *(bfx8*)(Cs + NN + off) = ls;
                } else if (cc < thr) {
                    #pragma unroll
                    for (int e = 0; e < 8; ++e)
                        if (cc + e < thr) {
                            float v = Ct[(cc + e) * 65 + rr];
                            u16 h = bf16_rne(v);
                            Cs[off + e]      = h;
                            Cs[NN + off + e] = bf16_rne(v - bf16_f(h));
                        }
                }
            }
        }
    }
    #undef STAGE
    #undef COMPUTE
}

// ---------------------------------------------------------------------------
// Schedule:
//   slots: O1=Arec, O2=R, O3=D (d_out); W1=ws[0:16M), W2=ws[16M:32M)
//   1. A2 = split(A)                    -> W1u
//   2. RT = build_right (R^T fp32)      -> O3 (scratch)
//   3. R2 -> W2u, RT2 -> O1u, R fp32 -> O2   (from RT)
//   4. G1: Ts  = split(R2 (*) A2^T)     -> O3u  [full, 256 blocks]
//   5. G2: D2  = split(mask(Ts (*) R2^T)) -> W1u [SYM, 272 blocks]
//   6. G3: T2s = split(RT2 (*) D2^T)    -> W2u  [full, 256 blocks]
//   7. D fp32 = unsplit(D2)             -> O3
//   8. park RT2: O1u -> W1u (d2d)
//   9. G4: Arec = T2s (*) RT2^T         -> O1 fp32 [SYM, 272 blocks]
// ws requirement: 32 MB.
// ---------------------------------------------------------------------------
extern "C" void kernel_launch(void* const* d_in, const int* in_sizes, int n_in,
                              void* d_out, int out_size, void* d_ws, size_t ws_size,
                              hipStream_t stream) {
    const float* A     = (const float*)d_in[0];
    const float* O_all = (const float*)d_in[1];
    const int*   sel   = (const int*)d_in[2];
    const int*   wav   = (const int*)d_in[3];
    const int    Lw    = in_sizes[3];

    float* O1 = (float*)d_out;          // Arec slot
    float* O2 = O1 + NN;                // R slot
    float* O3 = O1 + 2 * NN;            // D slot

    u16*   W1u = (u16*)d_ws;                                  // ws[0,16M)
    u16*   W2u = (u16*)((char*)d_ws + 2 * NN * sizeof(u16));  // ws[16M,32M)
    u16*   O1u = (u16*)O1;              // Arec slot as u16 scratch (RT2)
    u16*   O3u = (u16*)O3;              // D slot as u16 scratch (Ts)

    const int SGRID = (int)(NN / (256 * 8));

    split_plain_k<<<SGRID, 256, 0, stream>>>(A, W1u);                    // A2 -> W1
    build_right_k<<<N, 64, 0, stream>>>(O_all, sel, O3);                 // RT -> O3
    split_rt_k<<<(N / 64) * (N / 64), 256, 0, stream>>>(O3, W2u, O1u, O2); // R2,RT2,R

    gemm_bf3<0, 1, 0><<<256, 256, 0, stream>>>(W2u, W1u, nullptr, O3u, nullptr, 0); // Ts  -> O3
    gemm_bf3<1, 1, 1><<<272, 256, 0, stream>>>(O3u, W2u, nullptr, W1u, wav, Lw);    // D2  -> W1 (sym)
    gemm_bf3<0, 1, 0><<<256, 256, 0, stream>>>(O1u, W1u, nullptr, W2u, nullptr, 0); // T2s -> W2
    unsplit_k<<<SGRID, 256, 0, stream>>>(W1u, O3);                                  // D fp32 -> O3
    hipMemcpyAsync(W1u, O1u, 2 * NN * sizeof(u16), hipMemcpyDeviceToDevice, stream); // park RT2
    gemm_bf3<0, 0, 1><<<272, 256, 0, stream>>>(W2u, W1u, O1, nullptr, nullptr, 0);  // Arec -> O1 (sym)
}

// Round 10
// 326.741 us; speedup vs baseline: 1.0458x; 1.0458x over previous
//
#include <hip/hip_runtime.h>

#define N 2048
#define LEV 256
#define KS 16

typedef __attribute__((ext_vector_type(8))) short bfx8;
typedef __attribute__((ext_vector_type(4))) float fx4;
typedef unsigned short u16;
typedef unsigned int u32;

static const size_t NN = (size_t)N * N;

__device__ inline u16 bf16_rne(float f) {
    u32 u = __builtin_bit_cast(u32, f);
    u32 r = (u + 0x7FFFu + ((u >> 16) & 1u)) >> 16;
    return (u16)r;
}
__device__ inline float bf16_f(u16 h) {
    u32 u = ((u32)h) << 16;
    return __builtin_bit_cast(float, u);
}

// async global->LDS, 16B per lane. LDS dest = wave-uniform base + lane*16.
#define GLDS16(gp, lp) __builtin_amdgcn_global_load_lds( \
    (const __attribute__((address_space(1))) void*)(uintptr_t)(gp), \
    (__attribute__((address_space(3))) void*)(u32)(uintptr_t)(lp), 16, 0, 0)

// sum over the 4 lanes of each quad (lane^1 then lane^2), VALU-only via DPP.
__device__ inline float qadd(float x) {
#if __has_builtin(__builtin_amdgcn_mov_dpp)
    int a = __builtin_amdgcn_mov_dpp(__builtin_bit_cast(int, x), 0xB1, 0xF, 0xF, true);
    float y = x + __builtin_bit_cast(float, a);
    int b = __builtin_amdgcn_mov_dpp(__builtin_bit_cast(int, y), 0x4E, 0xF, 0xF, true);
    return y + __builtin_bit_cast(float, b);
#else
    float y = x + __shfl_xor(x, 1);
    return y + __shfl_xor(y, 2);
#endif
}

// ---------------------------------------------------------------------------
// build RT = (U_{L-1}...U_0)^T, ONE column per wave, 2-deep prefetch (R9).
// ---------------------------------------------------------------------------
__global__ __launch_bounds__(64)
void build_right_k(const float* __restrict__ O_all, const int* __restrict__ sel,
                   float* __restrict__ RT) {
    __shared__ float x[2048];
    const int lane = threadIdx.x;
    const int i    = lane >> 2;     // row 0..15
    const int kg   = lane & 3;      // k-quarter 0..3
    const int col  = blockIdx.x;

    const float4 z = make_float4(0.f, 0.f, 0.f, 0.f);
    #pragma unroll
    for (int q = 0; q < 8; ++q) *(float4*)&x[q * 256 + lane * 4] = z;
    if (lane == 0) x[col] = 1.0f;   // e_col; in-order DS, same wave

    const float* obase = O_all + i * KS + kg * 4;
    const int*   gbase = sel + kg * 4;

#define CMP(f, g, wv) { \
    float p = f.x * x[g.x] + f.y * x[g.y] + f.z * x[g.z] + f.w * x[g.w]; \
    p = qadd(p); \
    if (kg == 0) x[wv] = p; }

    float4 f0 = *(const float4*)(obase);
    int4   g0 = *(const int4*)(gbase);
    int    w0 = sel[i];
    float4 f1 = *(const float4*)(obase + 256);
    int4   g1 = *(const int4*)(gbase + KS);
    int    w1 = sel[KS + i];

    for (int l = 0; l < LEV; l += 2) {
        float4 f2, f3; int4 g2, g3; int w2, w3;
        if (l + 2 < LEV) {
            f2 = *(const float4*)(obase + (size_t)(l + 2) * 256);
            g2 = *(const int4*)(gbase + (l + 2) * KS);
            w2 = sel[(l + 2) * KS + i];
            f3 = *(const float4*)(obase + (size_t)(l + 3) * 256);
            g3 = *(const int4*)(gbase + (l + 3) * KS);
            w3 = sel[(l + 3) * KS + i];
        } else { f2 = f0; g2 = g0; w2 = w0; f3 = f1; g3 = g1; w3 = w1; }

        CMP(f0, g0, w0)
        CMP(f1, g1, w1)
        f0 = f2; g0 = g2; w0 = w2;
        f1 = f3; g1 = g3; w1 = w3;
    }
#undef CMP

    #pragma unroll
    for (int q = 0; q < 8; ++q)
        *(float4*)&RT[(size_t)col * N + q * 256 + lane * 4] =
            *(const float4*)&x[q * 256 + lane * 4];
}

// ---------------------------------------------------------------------------
// split fp32 matrix -> bf16 hi/lo planes (streaming)
// ---------------------------------------------------------------------------
__global__ __launch_bounds__(256)
void split_plain_k(const float* __restrict__ src, u16* __restrict__ dh) {
    u16* dl = dh + NN;
    size_t p = ((size_t)blockIdx.x * 256 + threadIdx.x) * 8;
    float4 v0 = *(const float4*)(src + p);
    float4 v1 = *(const float4*)(src + p + 4);
    float vv[8] = {v0.x, v0.y, v0.z, v0.w, v1.x, v1.y, v1.z, v1.w};
    bfx8 hs, ls;
    #pragma unroll
    for (int i = 0; i < 8; ++i) {
        u16 h = bf16_rne(vv[i]);
        hs[i] = (short)h;
        ls[i] = (short)bf16_rne(vv[i] - bf16_f(h));
    }
    *(bfx8*)(dh + p) = hs;
    *(bfx8*)(dl + p) = ls;
}

// ---------------------------------------------------------------------------
// From RT (= R^T row-major): R2 = split(R), RT2 = split(RT), R fp32 row-major.
// ---------------------------------------------------------------------------
__global__ __launch_bounds__(256)
void split_rt_k(const float* __restrict__ RT, u16* __restrict__ r2h,
                u16* __restrict__ rth, float* __restrict__ Rrm) {
    __shared__ float t[64][65];
    u16* r2l = r2h + NN;
    u16* rtl = rth + NN;
    const int r0 = (blockIdx.x >> 5) * 64, c0 = (blockIdx.x & 31) * 64;
    #pragma unroll
    for (int i = 0; i < 16; ++i) {
        int q = i * 256 + threadIdx.x;
        int rr = q >> 6, cc = q & 63;
        t[rr][cc] = RT[(size_t)(r0 + rr) * N + c0 + cc];
    }
    __syncthreads();
    #pragma unroll
    for (int i = 0; i < 16; ++i) {
        int q = i * 256 + threadIdx.x;
        int rr = q >> 6, cc = q & 63;
        float v = t[rr][cc];                        // RT[r0+rr][c0+cc]
        u16 h = bf16_rne(v);
        size_t po = (size_t)(r0 + rr) * N + c0 + cc;
        rth[po] = h;                                // split(RT)
        rtl[po] = bf16_rne(v - bf16_f(h));
        float w = t[cc][rr];                        // = R[c0+rr][r0+cc]
        u16 h2 = bf16_rne(w);
        size_t pt = (size_t)(c0 + rr) * N + r0 + cc;
        r2h[pt] = h2;                               // split(R)
        r2l[pt] = bf16_rne(w - bf16_f(h2));
        Rrm[pt] = w;                                // R fp32 (output slot)
    }
}

// ---------------------------------------------------------------------------
// D fp32 = hi + lo
// ---------------------------------------------------------------------------
__global__ __launch_bounds__(256)
void unsplit_k(const u16* __restrict__ hi, float* __restrict__ dst) {
    const u16* lo = hi + NN;
    size_t p = ((size_t)blockIdx.x * 256 + threadIdx.x) * 8;
    bfx8 hs = *(const bfx8*)(hi + p);
    bfx8 ls = *(const bfx8*)(lo + p);
    float4 o0, o1;
    o0.x = bf16_f((u16)hs[0]) + bf16_f((u16)ls[0]);
    o0.y = bf16_f((u16)hs[1]) + bf16_f((u16)ls[1]);
    o0.z = bf16_f((u16)hs[2]) + bf16_f((u16)ls[2]);
    o0.w = bf16_f((u16)hs[3]) + bf16_f((u16)ls[3]);
    o1.x = bf16_f((u16)hs[4]) + bf16_f((u16)ls[4]);
    o1.y = bf16_f((u16)hs[5]) + bf16_f((u16)ls[5]);
    o1.z = bf16_f((u16)hs[6]) + bf16_f((u16)ls[6]);
    o1.w = bf16_f((u16)hs[7]) + bf16_f((u16)ls[7]);
    *(float4*)(dst + p)     = o0;
    *(float4*)(dst + p + 4) = o1;
}

// ---------------------------------------------------------------------------
// C = X * Y^T via 3-term bf16 split MFMA.
// SINGLE-buffered global_load_lds staging, 64.5 KB LDS -> 2 blocks/CU:
// while one block drains its stage at the barrier, the co-resident block's
// MFMAs keep the SIMDs fed (m97/m114 implicit cross-block overlap).
// Both-sides XOR swizzle, 128x128 tile, BK=64, grid 256.
// ---------------------------------------------------------------------------
template<int MASKED, int OMODE>
__global__ __launch_bounds__(256, 2)
void gemm_bf3(const u16* __restrict__ Xp, const u16* __restrict__ Yp,
              float* __restrict__ Cf, u16* __restrict__ Cs,
              const int* __restrict__ wav, int Lw) {
    __shared__ __align__(16) u16 sm[4][8192];   // 64 KB single buffer
    __shared__ float rowf[128], colf[128];

    const int tid = threadIdx.x;
    // XCD-aware swizzle: 256 blocks, 8 XCDs, 32 contiguous per XCD (bijective)
    const int swz = ((blockIdx.x & 7) << 5) | (blockIdx.x >> 3);
    const int bx = swz & 15;
    const int by = swz >> 4;
    const int i0 = by * 128, j0 = bx * 128;
    const int lane = tid & 63, w = tid >> 6;
    const int wm = (w >> 1) * 64, wn = (w & 1) * 64;
    const int fr = lane & 15;

    if (MASKED) {
        if (tid < 128) rowf[tid] = 1.0f; else colf[tid - 128] = 1.0f;
        __syncthreads();
        for (int t = tid; t < Lw; t += 256) {
            int wv = wav[t];
            int dr = wv - i0; if (0 <= dr && dr < 128) rowf[dr] = 0.0f;
            int dc = wv - j0; if (0 <= dc && dc < 128) colf[dc] = 0.0f;
        }
        // consumed only in epilogue (after main-loop barriers)
    }

    fx4 acc[4][4];
    #pragma unroll
    for (int m = 0; m < 4; ++m)
        #pragma unroll
        for (int n = 0; n < 4; ++n)
            acc[m][n] = (fx4)0.0f;

    const u16* Xh = Xp; const u16* Xl = Xp + NN;
    const u16* Yh = Yp; const u16* Yl = Yp + NN;

    const int rl   = lane >> 3;
    const int gcol = ((lane & 7) ^ rl) << 3;
    const int wq   = w * 1024;

    #define STAGE(kt) { \
        const int k0s = (kt) * 64; \
        char* lb0 = (char*)&sm[0][0] + wq; \
        _Pragma("unroll") \
        for (int q = 0; q < 4; ++q) { \
            const int row = q * 32 + w * 8 + rl; \
            const size_t xo = (size_t)(i0 + row) * N + k0s + gcol; \
            const size_t yo = (size_t)(j0 + row) * N + k0s + gcol; \
            GLDS16(Xh + xo, lb0 + q * 4096); \
            GLDS16(Xl + xo, lb0 + 16384 + q * 4096); \
            GLDS16(Yh + yo, lb0 + 32768 + q * 4096); \
            GLDS16(Yl + yo, lb0 + 49152 + q * 4096); \
        } }

    const int kq  = (lane >> 4) << 4;
    const int frx = (fr & 7) << 4;

    #define COMPUTE() { \
        const char* base = (const char*)&sm[0][0]; \
        _Pragma("unroll") \
        for (int s = 0; s < 2; ++s) { \
            const int cb = s * 64 + kq; \
            bfx8 ah[4], al[4]; \
            _Pragma("unroll") \
            for (int m = 0; m < 4; ++m) { \
                const int off = (wm + m * 16 + fr) * 128 + (cb ^ frx); \
                ah[m] = *(const bfx8*)(base + off); \
                al[m] = *(const bfx8*)(base + 16384 + off); \
            } \
            _Pragma("unroll") \
            for (int n = 0; n < 4; ++n) { \
                const int off = (wn + n * 16 + fr) * 128 + (cb ^ frx); \
                bfx8 bh = *(const bfx8*)(base + 32768 + off); \
                bfx8 bl = *(const bfx8*)(base + 49152 + off); \
                _Pragma("unroll") \
                for (int m = 0; m < 4; ++m) { \
                    acc[m][n] = __builtin_amdgcn_mfma_f32_16x16x32_bf16(ah[m], bh, acc[m][n], 0, 0, 0); \
                    acc[m][n] = __builtin_amdgcn_mfma_f32_16x16x32_bf16(ah[m], bl, acc[m][n], 0, 0, 0); \
                    acc[m][n] = __builtin_amdgcn_mfma_f32_16x16x32_bf16(al[m], bh, acc[m][n], 0, 0, 0); \
                } \
            } \
        } }

    constexpr int NT = N / 64;
    for (int kt = 0; kt < NT; ++kt) {
        STAGE(kt)
        __syncthreads();        // drains vmcnt -> tile ready
        COMPUTE()
        __syncthreads();        // all reads done before next overwrite
    }

    // ---- epilogue: direct fragment stores (R5-proven clean) ----
    const int crow0 = (lane >> 4) * 4;
    #pragma unroll
    for (int m = 0; m < 4; ++m) {
        #pragma unroll
        for (int n = 0; n < 4; ++n) {
            #pragma unroll
            for (int r = 0; r < 4; ++r) {
                const int li = wm + m * 16 + crow0 + r;
                const int lj = wn + n * 16 + fr;
                float v = acc[m][n][r];
                if (MASKED) {
                    if (i0 + li != j0 + lj) v *= rowf[li] * colf[lj];
                }
                const size_t off = (size_t)(i0 + li) * N + j0 + lj;
                if (OMODE == 0) {
                    Cf[off] = v;
                } else {
                    u16 h = bf16_rne(v);
                    Cs[off]      = h;
                    Cs[NN + off] = bf16_rne(v - bf16_f(h));
                }
            }
        }
    }
    #undef STAGE
    #undef COMPUTE
}

// ---------------------------------------------------------------------------
// Schedule (R7-proven):
//   slots: O1=Arec, O2=R, O3=D (d_out); W1=ws[0:16M), W2=ws[16M:32M)
//   1. A2 = split(A)                    -> W1u
//   2. RT = build_right (R^T fp32)      -> O3 (scratch)
//   3. R2 -> W2u, RT2 -> O1u, R fp32 -> O2   (from RT)
//   4. G1: Ts  = split(R2 (*) A2^T)     -> O3u
//   5. G2: D2  = split(mask(Ts (*) R2^T)) -> W1u
//   6. G3: T2s = split(RT2 (*) D2^T)    -> W2u
//   7. D fp32 = unsplit(D2)             -> O3
//   8. park RT2: O1u -> W1u (d2d)
//   9. G4: Arec = T2s (*) RT2^T         -> O1 fp32
// ws requirement: 32 MB.
// ---------------------------------------------------------------------------
extern "C" void kernel_launch(void* const* d_in, const int* in_sizes, int n_in,
                              void* d_out, int out_size, void* d_ws, size_t ws_size,
                              hipStream_t stream) {
    const float* A     = (const float*)d_in[0];
    const float* O_all = (const float*)d_in[1];
    const int*   sel   = (const int*)d_in[2];
    const int*   wav   = (const int*)d_in[3];
    const int    Lw    = in_sizes[3];

    float* O1 = (float*)d_out;          // Arec slot
    float* O2 = O1 + NN;                // R slot
    float* O3 = O1 + 2 * NN;            // D slot

    u16*   W1u = (u16*)d_ws;                                  // ws[0,16M)
    u16*   W2u = (u16*)((char*)d_ws + 2 * NN * sizeof(u16));  // ws[16M,32M)
    u16*   O1u = (u16*)O1;              // Arec slot as u16 scratch (RT2)
    u16*   O3u = (u16*)O3;              // D slot as u16 scratch (Ts)

    const int SGRID = (int)(NN / (256 * 8));

    split_plain_k<<<SGRID, 256, 0, stream>>>(A, W1u);                    // A2 -> W1
    build_right_k<<<N, 64, 0, stream>>>(O_all, sel, O3);                 // RT -> O3
    split_rt_k<<<(N / 64) * (N / 64), 256, 0, stream>>>(O3, W2u, O1u, O2); // R2,RT2,R

    gemm_bf3<0, 1><<<256, 256, 0, stream>>>(W2u, W1u, nullptr, O3u, nullptr, 0); // Ts  -> O3
    gemm_bf3<1, 1><<<256, 256, 0, stream>>>(O3u, W2u, nullptr, W1u, wav, Lw);    // D2  -> W1
    gemm_bf3<0, 1><<<256, 256, 0, stream>>>(O1u, W1u, nullptr, W2u, nullptr, 0); // T2s -> W2
    unsplit_k<<<SGRID, 256, 0, stream>>>(W1u, O3);                               // D fp32 -> O3
    hipMemcpyAsync(W1u, O1u, 2 * NN * sizeof(u16), hipMemcpyDeviceToDevice, stream); // park RT2
    gemm_bf3<0, 0><<<256, 256, 0, stream>>>(W2u, W1u, O1, nullptr, nullptr, 0);  // Arec -> O1
}

// Round 11
// 298.300 us; speedup vs baseline: 1.1455x; 1.0953x over previous
//
#include <hip/hip_runtime.h>

#define N 2048
#define LEV 256
#define KS 16

typedef __attribute__((ext_vector_type(8))) short bfx8;
typedef __attribute__((ext_vector_type(4))) float fx4;
typedef unsigned short u16;
typedef unsigned int u32;

static const size_t NN = (size_t)N * N;

__device__ inline u16 bf16_rne(float f) {
    u32 u = __builtin_bit_cast(u32, f);
    u32 r = (u + 0x7FFFu + ((u >> 16) & 1u)) >> 16;
    return (u16)r;
}
__device__ inline float bf16_f(u16 h) {
    u32 u = ((u32)h) << 16;
    return __builtin_bit_cast(float, u);
}

// async global->LDS, 16B per lane. LDS dest = wave-uniform base + lane*16.
#define GLDS16(gp, lp) __builtin_amdgcn_global_load_lds( \
    (const __attribute__((address_space(1))) void*)(uintptr_t)(gp), \
    (__attribute__((address_space(3))) void*)(u32)(uintptr_t)(lp), 16, 0, 0)

// sum over the 4 lanes of each quad (lane^1 then lane^2), VALU-only via DPP.
__device__ inline float qadd(float x) {
#if __has_builtin(__builtin_amdgcn_mov_dpp)
    int a = __builtin_amdgcn_mov_dpp(__builtin_bit_cast(int, x), 0xB1, 0xF, 0xF, true);
    float y = x + __builtin_bit_cast(float, a);
    int b = __builtin_amdgcn_mov_dpp(__builtin_bit_cast(int, y), 0x4E, 0xF, 0xF, true);
    return y + __builtin_bit_cast(float, b);
#else
    float y = x + __shfl_xor(x, 1);
    return y + __shfl_xor(y, 2);
#endif
}

// ---------------------------------------------------------------------------
// build RT = (U_{L-1}...U_0)^T, ONE column per wave, 2-deep prefetch (R9).
// ---------------------------------------------------------------------------
__global__ __launch_bounds__(64)
void build_right_k(const float* __restrict__ O_all, const int* __restrict__ sel,
                   float* __restrict__ RT) {
    __shared__ float x[2048];
    const int lane = threadIdx.x;
    const int i    = lane >> 2;     // row 0..15
    const int kg   = lane & 3;      // k-quarter 0..3
    const int col  = blockIdx.x;

    const float4 z = make_float4(0.f, 0.f, 0.f, 0.f);
    #pragma unroll
    for (int q = 0; q < 8; ++q) *(float4*)&x[q * 256 + lane * 4] = z;
    if (lane == 0) x[col] = 1.0f;   // e_col; in-order DS, same wave

    const float* obase = O_all + i * KS + kg * 4;
    const int*   gbase = sel + kg * 4;

#define CMP(f, g, wv) { \
    float p = f.x * x[g.x] + f.y * x[g.y] + f.z * x[g.z] + f.w * x[g.w]; \
    p = qadd(p); \
    if (kg == 0) x[wv] = p; }

    float4 f0 = *(const float4*)(obase);
    int4   g0 = *(const int4*)(gbase);
    int    w0 = sel[i];
    float4 f1 = *(const float4*)(obase + 256);
    int4   g1 = *(const int4*)(gbase + KS);
    int    w1 = sel[KS + i];

    for (int l = 0; l < LEV; l += 2) {
        float4 f2, f3; int4 g2, g3; int w2, w3;
        if (l + 2 < LEV) {
            f2 = *(const float4*)(obase + (size_t)(l + 2) * 256);
            g2 = *(const int4*)(gbase + (l + 2) * KS);
            w2 = sel[(l + 2) * KS + i];
            f3 = *(const float4*)(obase + (size_t)(l + 3) * 256);
            g3 = *(const int4*)(gbase + (l + 3) * KS);
            w3 = sel[(l + 3) * KS + i];
        } else { f2 = f0; g2 = g0; w2 = w0; f3 = f1; g3 = g1; w3 = w1; }

        CMP(f0, g0, w0)
        CMP(f1, g1, w1)
        f0 = f2; g0 = g2; w0 = w2;
        f1 = f3; g1 = g3; w1 = w3;
    }
#undef CMP

    #pragma unroll
    for (int q = 0; q < 8; ++q)
        *(float4*)&RT[(size_t)col * N + q * 256 + lane * 4] =
            *(const float4*)&x[q * 256 + lane * 4];
}

// ---------------------------------------------------------------------------
// split fp32 matrix -> bf16 hi/lo planes (streaming)
// ---------------------------------------------------------------------------
__global__ __launch_bounds__(256)
void split_plain_k(const float* __restrict__ src, u16* __restrict__ dh) {
    u16* dl = dh + NN;
    size_t p = ((size_t)blockIdx.x * 256 + threadIdx.x) * 8;
    float4 v0 = *(const float4*)(src + p);
    float4 v1 = *(const float4*)(src + p + 4);
    float vv[8] = {v0.x, v0.y, v0.z, v0.w, v1.x, v1.y, v1.z, v1.w};
    bfx8 hs, ls;
    #pragma unroll
    for (int i = 0; i < 8; ++i) {
        u16 h = bf16_rne(vv[i]);
        hs[i] = (short)h;
        ls[i] = (short)bf16_rne(vv[i] - bf16_f(h));
    }
    *(bfx8*)(dh + p) = hs;
    *(bfx8*)(dl + p) = ls;
}

// ---------------------------------------------------------------------------
// From RT (= R^T row-major): R2 = split(R), RT2 = split(RT), R fp32 row-major.
// ---------------------------------------------------------------------------
__global__ __launch_bounds__(256)
void split_rt_k(const float* __restrict__ RT, u16* __restrict__ r2h,
                u16* __restrict__ rth, float* __restrict__ Rrm) {
    __shared__ float t[64][65];
    u16* r2l = r2h + NN;
    u16* rtl = rth + NN;
    const int r0 = (blockIdx.x >> 5) * 64, c0 = (blockIdx.x & 31) * 64;
    #pragma unroll
    for (int i = 0; i < 16; ++i) {
        int q = i * 256 + threadIdx.x;
        int rr = q >> 6, cc = q & 63;
        t[rr][cc] = RT[(size_t)(r0 + rr) * N + c0 + cc];
    }
    __syncthreads();
    #pragma unroll
    for (int i = 0; i < 16; ++i) {
        int q = i * 256 + threadIdx.x;
        int rr = q >> 6, cc = q & 63;
        float v = t[rr][cc];                        // RT[r0+rr][c0+cc]
        u16 h = bf16_rne(v);
        size_t po = (size_t)(r0 + rr) * N + c0 + cc;
        rth[po] = h;                                // split(RT)
        rtl[po] = bf16_rne(v - bf16_f(h));
        float w = t[cc][rr];                        // = R[c0+rr][r0+cc]
        u16 h2 = bf16_rne(w);
        size_t pt = (size_t)(c0 + rr) * N + r0 + cc;
        r2h[pt] = h2;                               // split(R)
        r2l[pt] = bf16_rne(w - bf16_f(h2));
        Rrm[pt] = w;                                // R fp32 (output slot)
    }
}

// ---------------------------------------------------------------------------
// D fp32 = hi + lo
// ---------------------------------------------------------------------------
__global__ __launch_bounds__(256)
void unsplit_k(const u16* __restrict__ hi, float* __restrict__ dst) {
    const u16* lo = hi + NN;
    size_t p = ((size_t)blockIdx.x * 256 + threadIdx.x) * 8;
    bfx8 hs = *(const bfx8*)(hi + p);
    bfx8 ls = *(const bfx8*)(lo + p);
    float4 o0, o1;
    o0.x = bf16_f((u16)hs[0]) + bf16_f((u16)ls[0]);
    o0.y = bf16_f((u16)hs[1]) + bf16_f((u16)ls[1]);
    o0.z = bf16_f((u16)hs[2]) + bf16_f((u16)ls[2]);
    o0.w = bf16_f((u16)hs[3]) + bf16_f((u16)ls[3]);
    o1.x = bf16_f((u16)hs[4]) + bf16_f((u16)ls[4]);
    o1.y = bf16_f((u16)hs[5]) + bf16_f((u16)ls[5]);
    o1.z = bf16_f((u16)hs[6]) + bf16_f((u16)ls[6]);
    o1.w = bf16_f((u16)hs[7]) + bf16_f((u16)ls[7]);
    *(float4*)(dst + p)     = o0;
    *(float4*)(dst + p + 4) = o1;
}

// ---------------------------------------------------------------------------
// C = X * Y^T via 3-term bf16 split MFMA. R6/R7-proven double-buffered
// global_load_lds staging (128 KB LDS, 1 barrier/kt), both-sides XOR swizzle,
// 128x128 tile, BK=64, grid 256.
// SYNCV=1 (A/B experiment, G3 only): raw s_barrier + counted vmcnt(16) so the
// 16 next-tile loads stay in flight across the barrier (no vmcnt(0) drain).
// ---------------------------------------------------------------------------
template<int MASKED, int OMODE, int SYNCV>
__global__ __launch_bounds__(256)
void gemm_bf3(const u16* __restrict__ Xp, const u16* __restrict__ Yp,
              float* __restrict__ Cf, u16* __restrict__ Cs,
              const int* __restrict__ wav, int Lw) {
    __shared__ __align__(16) u16 sm[2][4][8192];   // 128 KB double buffer
    __shared__ float rowf[128], colf[128];

    const int tid = threadIdx.x;
    // XCD-aware swizzle: 256 blocks, 8 XCDs, 32 contiguous per XCD (bijective)
    const int swz = ((blockIdx.x & 7) << 5) | (blockIdx.x >> 3);
    const int bx = swz & 15;
    const int by = swz >> 4;
    const int i0 = by * 128, j0 = bx * 128;
    const int lane = tid & 63, w = tid >> 6;
    const int wm = (w >> 1) * 64, wn = (w & 1) * 64;
    const int fr = lane & 15;

    if (MASKED) {
        if (tid < 128) rowf[tid] = 1.0f; else colf[tid - 128] = 1.0f;
        __syncthreads();
        for (int t = tid; t < Lw; t += 256) {
            int wv = wav[t];
            int dr = wv - i0; if (0 <= dr && dr < 128) rowf[dr] = 0.0f;
            int dc = wv - j0; if (0 <= dc && dc < 128) colf[dc] = 0.0f;
        }
        // consumed only in epilogue (after main-loop barriers)
    }

    fx4 acc[4][4];
    #pragma unroll
    for (int m = 0; m < 4; ++m)
        #pragma unroll
        for (int n = 0; n < 4; ++n)
            acc[m][n] = (fx4)0.0f;

    const u16* Xh = Xp; const u16* Xl = Xp + NN;
    const u16* Yh = Yp; const u16* Yl = Yp + NN;

    const int rl   = lane >> 3;
    const int gcol = ((lane & 7) ^ rl) << 3;
    const int wq   = w * 1024;

    #define STAGE(buf, kt) { \
        const int k0s = (kt) * 64; \
        char* lb0 = (char*)&sm[buf][0][0] + wq; \
        _Pragma("unroll") \
        for (int q = 0; q < 4; ++q) { \
            const int row = q * 32 + w * 8 + rl; \
            const size_t xo = (size_t)(i0 + row) * N + k0s + gcol; \
            const size_t yo = (size_t)(j0 + row) * N + k0s + gcol; \
            GLDS16(Xh + xo, lb0 + q * 4096); \
            GLDS16(Xl + xo, lb0 + 16384 + q * 4096); \
            GLDS16(Yh + yo, lb0 + 32768 + q * 4096); \
            GLDS16(Yl + yo, lb0 + 49152 + q * 4096); \
        } }

    const int kq  = (lane >> 4) << 4;
    const int frx = (fr & 7) << 4;

    #define COMPUTE(buf) { \
        const char* base = (const char*)&sm[buf][0][0]; \
        _Pragma("unroll") \
        for (int s = 0; s < 2; ++s) { \
            const int cb = s * 64 + kq; \
            bfx8 ah[4], al[4]; \
            _Pragma("unroll") \
            for (int m = 0; m < 4; ++m) { \
                const int off = (wm + m * 16 + fr) * 128 + (cb ^ frx); \
                ah[m] = *(const bfx8*)(base + off); \
                al[m] = *(const bfx8*)(base + 16384 + off); \
            } \
            _Pragma("unroll") \
            for (int n = 0; n < 4; ++n) { \
                const int off = (wn + n * 16 + fr) * 128 + (cb ^ frx); \
                bfx8 bh = *(const bfx8*)(base + 32768 + off); \
                bfx8 bl = *(const bfx8*)(base + 49152 + off); \
                _Pragma("unroll") \
                for (int m = 0; m < 4; ++m) { \
                    acc[m][n] = __builtin_amdgcn_mfma_f32_16x16x32_bf16(ah[m], bh, acc[m][n], 0, 0, 0); \
                    acc[m][n] = __builtin_amdgcn_mfma_f32_16x16x32_bf16(ah[m], bl, acc[m][n], 0, 0, 0); \
                    acc[m][n] = __builtin_amdgcn_mfma_f32_16x16x32_bf16(al[m], bh, acc[m][n], 0, 0, 0); \
                } \
            } \
        } }

    constexpr int NT = N / 64;
    STAGE(0, 0)
    if (SYNCV == 0) {
        __syncthreads();                      // drains vmcnt -> buf0 ready
        for (int kt = 0; kt < NT; ++kt) {
            const int cur = kt & 1;
            if (kt + 1 < NT) STAGE(cur ^ 1, kt + 1)   // loads fly during compute
            COMPUTE(cur)
            __syncthreads();                  // drain + reuse protection
        }
    } else {
        for (int kt = 0; kt < NT; ++kt) {
            const int cur = kt & 1;
            if (kt + 1 < NT) {
                STAGE(cur ^ 1, kt + 1)        // 16 more in flight (32 total)
                asm volatile("s_waitcnt vmcnt(16)" ::: "memory"); // cur's 16 done
            } else {
                asm volatile("s_waitcnt vmcnt(0)" ::: "memory");  // tail: drain
            }
            __builtin_amdgcn_sched_barrier(0);
            __builtin_amdgcn_s_barrier();     // align waves; no drain
            __builtin_amdgcn_sched_barrier(0);
            COMPUTE(cur)
            __builtin_amdgcn_sched_barrier(0);
            __builtin_amdgcn_s_barrier();     // reads done before buf reuse
            __builtin_amdgcn_sched_barrier(0);
        }
    }

    // ---- epilogue: direct fragment stores (R5-proven clean) ----
    const int crow0 = (lane >> 4) * 4;
    #pragma unroll
    for (int m = 0; m < 4; ++m) {
        #pragma unroll
        for (int n = 0; n < 4; ++n) {
            #pragma unroll
            for (int r = 0; r < 4; ++r) {
                const int li = wm + m * 16 + crow0 + r;
                const int lj = wn + n * 16 + fr;
                float v = acc[m][n][r];
                if (MASKED) {
                    if (i0 + li != j0 + lj) v *= rowf[li] * colf[lj];
                }
                const size_t off = (size_t)(i0 + li) * N + j0 + lj;
                if (OMODE == 0) {
                    Cf[off] = v;
                } else {
                    u16 h = bf16_rne(v);
                    Cs[off]      = h;
                    Cs[NN + off] = bf16_rne(v - bf16_f(h));
                }
            }
        }
    }
    #undef STAGE
    #undef COMPUTE
}

// ---------------------------------------------------------------------------
// Schedule (park-free slot plan, lifetime-verified):
//   slots: O1=Arec, O2=R, O3=D (d_out); W1=ws[0:16M), W2=ws[16M:32M)
//   1. A2 = split(A)                 -> W2u   [dies after G1]
//   2. RT = build_right (R^T fp32)   -> O3    [dies after split_rt]
//   3. split_rt: R2 -> O1u, RT2 -> W1u, R fp32 -> O2
//   4. G1: Ts  = split(R2 ⊛ A2^T)    -> O3u   [RT dead]
//   5. G2: D2  = split(mask(Ts ⊛ R2^T)) -> W2u [A2 dead]
//   6. G3: T2s = split(RT2 ⊛ D2^T)   -> O3u   [Ts dead]   (SYNCV=1 A/B)
//   7. G4: Arec = T2s ⊛ RT2^T        -> O1 fp32 [R2 dead]
//   8. unsplit: D fp32 = D2(W2u)     -> O3    [T2s, RT2 dead]
// ws requirement: 32 MB. No d2d copies.
// ---------------------------------------------------------------------------
extern "C" void kernel_launch(void* const* d_in, const int* in_sizes, int n_in,
                              void* d_out, int out_size, void* d_ws, size_t ws_size,
                              hipStream_t stream) {
    const float* A     = (const float*)d_in[0];
    const float* O_all = (const float*)d_in[1];
    const int*   sel   = (const int*)d_in[2];
    const int*   wav   = (const int*)d_in[3];
    const int    Lw    = in_sizes[3];

    float* O1 = (float*)d_out;          // Arec slot
    float* O2 = O1 + NN;                // R slot
    float* O3 = O1 + 2 * NN;            // D slot

    u16*   W1u = (u16*)d_ws;                                  // ws[0,16M)
    u16*   W2u = (u16*)((char*)d_ws + 2 * NN * sizeof(u16));  // ws[16M,32M)
    u16*   O1u = (u16*)O1;
    u16*   O3u = (u16*)O3;

    const int SGRID = (int)(NN / (256 * 8));

    split_plain_k<<<SGRID, 256, 0, stream>>>(A, W2u);                      // A2 -> W2
    build_right_k<<<N, 64, 0, stream>>>(O_all, sel, O3);                   // RT -> O3
    split_rt_k<<<(N / 64) * (N / 64), 256, 0, stream>>>(O3, O1u, W1u, O2); // R2->O1u, RT2->W1u, R->O2

    gemm_bf3<0, 1, 0><<<256, 256, 0, stream>>>(O1u, W2u, nullptr, O3u, nullptr, 0); // G1: Ts  -> O3u
    gemm_bf3<1, 1, 0><<<256, 256, 0, stream>>>(O3u, O1u, nullptr, W2u, wav, Lw);    // G2: D2  -> W2u
    gemm_bf3<0, 1, 1><<<256, 256, 0, stream>>>(W1u, W2u, nullptr, O3u, nullptr, 0); // G3: T2s -> O3u (counted-vmcnt A/B)
    gemm_bf3<0, 0, 0><<<256, 256, 0, stream>>>(O3u, W1u, O1, nullptr, nullptr, 0);  // G4: Arec -> O1
    unsplit_k<<<SGRID, 256, 0, stream>>>(W2u, O3);                                  // D fp32 -> O3
}

// Round 12
// 290.356 us; speedup vs baseline: 1.1768x; 1.0274x over previous
//
#include <hip/hip_runtime.h>

#define N 2048
#define LEV 256
#define KS 16

typedef __attribute__((ext_vector_type(8))) short bfx8;
typedef __attribute__((ext_vector_type(4))) float fx4;
typedef unsigned short u16;
typedef unsigned int u32;

static const size_t NN = (size_t)N * N;

__device__ inline u16 bf16_rne(float f) {
    u32 u = __builtin_bit_cast(u32, f);
    u32 r = (u + 0x7FFFu + ((u >> 16) & 1u)) >> 16;
    return (u16)r;
}
__device__ inline float bf16_f(u16 h) {
    u32 u = ((u32)h) << 16;
    return __builtin_bit_cast(float, u);
}

// async global->LDS, 16B per lane. LDS dest = wave-uniform base + lane*16.
#define GLDS16(gp, lp) __builtin_amdgcn_global_load_lds( \
    (const __attribute__((address_space(1))) void*)(uintptr_t)(gp), \
    (__attribute__((address_space(3))) void*)(u32)(uintptr_t)(lp), 16, 0, 0)

// sum over the 4 lanes of each quad (lane^1 then lane^2), VALU-only via DPP.
__device__ inline float qadd(float x) {
#if __has_builtin(__builtin_amdgcn_mov_dpp)
    int a = __builtin_amdgcn_mov_dpp(__builtin_bit_cast(int, x), 0xB1, 0xF, 0xF, true);
    float y = x + __builtin_bit_cast(float, a);
    int b = __builtin_amdgcn_mov_dpp(__builtin_bit_cast(int, y), 0x4E, 0xF, 0xF, true);
    return y + __builtin_bit_cast(float, b);
#else
    float y = x + __shfl_xor(x, 1);
    return y + __shfl_xor(y, 2);
#endif
}

// ---------------------------------------------------------------------------
// build RT = (U_{L-1}...U_0)^T. TWO columns per wave (two independent
// gather->reduce->scatter chains interleave in one wave; sel/O shared),
// 16.4 KB LDS keeps 8 blocks/CU (R8's 33KB/4-col occupancy cliff avoided).
// 2-deep prefetch of O/sel. Single wave -> DS program order, no barriers.
// ---------------------------------------------------------------------------
__global__ __launch_bounds__(64)
void build_right_k(const float* __restrict__ O_all, const int* __restrict__ sel,
                   float* __restrict__ RT) {
    __shared__ float x[2][2052];
    const int lane = threadIdx.x;
    const int i    = lane >> 2;     // row 0..15
    const int kg   = lane & 3;      // k-quarter 0..3
    const int col0 = blockIdx.x * 2;

    const float4 z = make_float4(0.f, 0.f, 0.f, 0.f);
    #pragma unroll
    for (int q = 0; q < 8; ++q) {
        *(float4*)&x[0][q * 256 + lane * 4] = z;
        *(float4*)&x[1][q * 256 + lane * 4] = z;
    }
    if (lane < 2) x[lane][col0 + lane] = 1.0f;   // e_{col0+c}; in-order DS

    const float* obase = O_all + i * KS + kg * 4;
    const int*   gbase = sel + kg * 4;

#define CMP(f, g, wv) { \
    float p0 = f.x * x[0][g.x] + f.y * x[0][g.y] + f.z * x[0][g.z] + f.w * x[0][g.w]; \
    float p1 = f.x * x[1][g.x] + f.y * x[1][g.y] + f.z * x[1][g.z] + f.w * x[1][g.w]; \
    p0 = qadd(p0); p1 = qadd(p1); \
    if (kg == 0) { x[0][wv] = p0; x[1][wv] = p1; } }

    float4 f0 = *(const float4*)(obase);
    int4   g0 = *(const int4*)(gbase);
    int    w0 = sel[i];
    float4 f1 = *(const float4*)(obase + 256);
    int4   g1 = *(const int4*)(gbase + KS);
    int    w1 = sel[KS + i];

    for (int l = 0; l < LEV; l += 2) {
        float4 f2, f3; int4 g2, g3; int w2, w3;
        if (l + 2 < LEV) {
            f2 = *(const float4*)(obase + (size_t)(l + 2) * 256);
            g2 = *(const int4*)(gbase + (l + 2) * KS);
            w2 = sel[(l + 2) * KS + i];
            f3 = *(const float4*)(obase + (size_t)(l + 3) * 256);
            g3 = *(const int4*)(gbase + (l + 3) * KS);
            w3 = sel[(l + 3) * KS + i];
        } else { f2 = f0; g2 = g0; w2 = w0; f3 = f1; g3 = g1; w3 = w1; }

        CMP(f0, g0, w0)
        CMP(f1, g1, w1)
        f0 = f2; g0 = g2; w0 = w2;
        f1 = f3; g1 = g3; w1 = w3;
    }
#undef CMP

    #pragma unroll
    for (int c = 0; c < 2; ++c)
        #pragma unroll
        for (int q = 0; q < 8; ++q)
            *(float4*)&RT[(size_t)(col0 + c) * N + q * 256 + lane * 4] =
                *(const float4*)&x[c][q * 256 + lane * 4];
}

// ---------------------------------------------------------------------------
// split fp32 matrix -> bf16 hi/lo planes (streaming)
// ---------------------------------------------------------------------------
__global__ __launch_bounds__(256)
void split_plain_k(const float* __restrict__ src, u16* __restrict__ dh) {
    u16* dl = dh + NN;
    size_t p = ((size_t)blockIdx.x * 256 + threadIdx.x) * 8;
    float4 v0 = *(const float4*)(src + p);
    float4 v1 = *(const float4*)(src + p + 4);
    float vv[8] = {v0.x, v0.y, v0.z, v0.w, v1.x, v1.y, v1.z, v1.w};
    bfx8 hs, ls;
    #pragma unroll
    for (int i = 0; i < 8; ++i) {
        u16 h = bf16_rne(vv[i]);
        hs[i] = (short)h;
        ls[i] = (short)bf16_rne(vv[i] - bf16_f(h));
    }
    *(bfx8*)(dh + p) = hs;
    *(bfx8*)(dl + p) = ls;
}

// ---------------------------------------------------------------------------
// From RT (= R^T row-major): R2 = split(R), RT2 = split(RT), R fp32 row-major.
// ---------------------------------------------------------------------------
__global__ __launch_bounds__(256)
void split_rt_k(const float* __restrict__ RT, u16* __restrict__ r2h,
                u16* __restrict__ rth, float* __restrict__ Rrm) {
    __shared__ float t[64][65];
    u16* r2l = r2h + NN;
    u16* rtl = rth + NN;
    const int r0 = (blockIdx.x >> 5) * 64, c0 = (blockIdx.x & 31) * 64;
    #pragma unroll
    for (int i = 0; i < 16; ++i) {
        int q = i * 256 + threadIdx.x;
        int rr = q >> 6, cc = q & 63;
        t[rr][cc] = RT[(size_t)(r0 + rr) * N + c0 + cc];
    }
    __syncthreads();
    #pragma unroll
    for (int i = 0; i < 16; ++i) {
        int q = i * 256 + threadIdx.x;
        int rr = q >> 6, cc = q & 63;
        float v = t[rr][cc];                        // RT[r0+rr][c0+cc]
        u16 h = bf16_rne(v);
        size_t po = (size_t)(r0 + rr) * N + c0 + cc;
        rth[po] = h;                                // split(RT)
        rtl[po] = bf16_rne(v - bf16_f(h));
        float w = t[cc][rr];                        // = R[c0+rr][r0+cc]
        u16 h2 = bf16_rne(w);
        size_t pt = (size_t)(c0 + rr) * N + r0 + cc;
        r2h[pt] = h2;                               // split(R)
        r2l[pt] = bf16_rne(w - bf16_f(h2));
        Rrm[pt] = w;                                // R fp32 (output slot)
    }
}

// ---------------------------------------------------------------------------
// D fp32 = hi + lo
// ---------------------------------------------------------------------------
__global__ __launch_bounds__(256)
void unsplit_k(const u16* __restrict__ hi, float* __restrict__ dst) {
    const u16* lo = hi + NN;
    size_t p = ((size_t)blockIdx.x * 256 + threadIdx.x) * 8;
    bfx8 hs = *(const bfx8*)(hi + p);
    bfx8 ls = *(const bfx8*)(lo + p);
    float4 o0, o1;
    o0.x = bf16_f((u16)hs[0]) + bf16_f((u16)ls[0]);
    o0.y = bf16_f((u16)hs[1]) + bf16_f((u16)ls[1]);
    o0.z = bf16_f((u16)hs[2]) + bf16_f((u16)ls[2]);
    o0.w = bf16_f((u16)hs[3]) + bf16_f((u16)ls[3]);
    o1.x = bf16_f((u16)hs[4]) + bf16_f((u16)ls[4]);
    o1.y = bf16_f((u16)hs[5]) + bf16_f((u16)ls[5]);
    o1.z = bf16_f((u16)hs[6]) + bf16_f((u16)ls[6]);
    o1.w = bf16_f((u16)hs[7]) + bf16_f((u16)ls[7]);
    *(float4*)(dst + p)     = o0;
    *(float4*)(dst + p + 4) = o1;
}

// ---------------------------------------------------------------------------
// C = X * Y^T via 3-term bf16 split MFMA. R6/R7-proven double-buffered
// global_load_lds staging, both-sides XOR swizzle, 128x128 tile, BK=64.
// NEW: 4x4-per-XCD super-tile block swizzle (bijective) — per-XCD working
// set 18 MB -> 8 MB (X and Y panels each shared by 4 in-XCD blocks) to cut
// HBM re-fetch and the ~900cy miss-latency stalls at the drain barrier.
// ---------------------------------------------------------------------------
template<int MASKED, int OMODE>
__global__ __launch_bounds__(256)
void gemm_bf3(const u16* __restrict__ Xp, const u16* __restrict__ Yp,
              float* __restrict__ Cf, u16* __restrict__ Cs,
              const int* __restrict__ wav, int Lw) {
    __shared__ __align__(16) u16 sm[2][4][8192];   // 128 KB double buffer
    __shared__ float rowf[128], colf[128];

    const int tid = threadIdx.x;
    // 4x4 super-tile per XCD: xcd = bid&7 owns super-tiles {2*xcd, 2*xcd+1}
    const int xcd = blockIdx.x & 7, idx = blockIdx.x >> 3;      // idx 0..31
    const int sup = 2 * xcd + (idx >> 4);                       // 0..15
    const int wi4 = idx & 15;
    const int by = ((sup >> 2) << 2) | (wi4 >> 2);              // 0..15
    const int bx = ((sup & 3) << 2) | (wi4 & 3);                // 0..15
    const int i0 = by * 128, j0 = bx * 128;
    const int lane = tid & 63, w = tid >> 6;
    const int wm = (w >> 1) * 64, wn = (w & 1) * 64;
    const int fr = lane & 15;

    if (MASKED) {
        if (tid < 128) rowf[tid] = 1.0f; else colf[tid - 128] = 1.0f;
        __syncthreads();
        for (int t = tid; t < Lw; t += 256) {
            int wv = wav[t];
            int dr = wv - i0; if (0 <= dr && dr < 128) rowf[dr] = 0.0f;
            int dc = wv - j0; if (0 <= dc && dc < 128) colf[dc] = 0.0f;
        }
        // consumed only in epilogue (after main-loop barriers)
    }

    fx4 acc[4][4];
    #pragma unroll
    for (int m = 0; m < 4; ++m)
        #pragma unroll
        for (int n = 0; n < 4; ++n)
            acc[m][n] = (fx4)0.0f;

    const u16* Xh = Xp; const u16* Xl = Xp + NN;
    const u16* Yh = Yp; const u16* Yl = Yp + NN;

    const int rl   = lane >> 3;
    const int gcol = ((lane & 7) ^ rl) << 3;
    const int wq   = w * 1024;

    #define STAGE(buf, kt) { \
        const int k0s = (kt) * 64; \
        char* lb0 = (char*)&sm[buf][0][0] + wq; \
        _Pragma("unroll") \
        for (int q = 0; q < 4; ++q) { \
            const int row = q * 32 + w * 8 + rl; \
            const size_t xo = (size_t)(i0 + row) * N + k0s + gcol; \
            const size_t yo = (size_t)(j0 + row) * N + k0s + gcol; \
            GLDS16(Xh + xo, lb0 + q * 4096); \
            GLDS16(Xl + xo, lb0 + 16384 + q * 4096); \
            GLDS16(Yh + yo, lb0 + 32768 + q * 4096); \
            GLDS16(Yl + yo, lb0 + 49152 + q * 4096); \
        } }

    const int kq  = (lane >> 4) << 4;
    const int frx = (fr & 7) << 4;

    #define COMPUTE(buf) { \
        const char* base = (const char*)&sm[buf][0][0]; \
        _Pragma("unroll") \
        for (int s = 0; s < 2; ++s) { \
            const int cb = s * 64 + kq; \
            bfx8 ah[4], al[4]; \
            _Pragma("unroll") \
            for (int m = 0; m < 4; ++m) { \
                const int off = (wm + m * 16 + fr) * 128 + (cb ^ frx); \
                ah[m] = *(const bfx8*)(base + off); \
                al[m] = *(const bfx8*)(base + 16384 + off); \
            } \
            _Pragma("unroll") \
            for (int n = 0; n < 4; ++n) { \
                const int off = (wn + n * 16 + fr) * 128 + (cb ^ frx); \
                bfx8 bh = *(const bfx8*)(base + 32768 + off); \
                bfx8 bl = *(const bfx8*)(base + 49152 + off); \
                _Pragma("unroll") \
                for (int m = 0; m < 4; ++m) { \
                    acc[m][n] = __builtin_amdgcn_mfma_f32_16x16x32_bf16(ah[m], bh, acc[m][n], 0, 0, 0); \
                    acc[m][n] = __builtin_amdgcn_mfma_f32_16x16x32_bf16(ah[m], bl, acc[m][n], 0, 0, 0); \
                    acc[m][n] = __builtin_amdgcn_mfma_f32_16x16x32_bf16(al[m], bh, acc[m][n], 0, 0, 0); \
                } \
            } \
        } }

    constexpr int NT = N / 64;
    STAGE(0, 0)
    __syncthreads();                      // drains vmcnt -> buf0 ready
    for (int kt = 0; kt < NT; ++kt) {
        const int cur = kt & 1;
        if (kt + 1 < NT) STAGE(cur ^ 1, kt + 1)   // loads fly during compute
        COMPUTE(cur)
        __syncthreads();                  // drain + reuse protection
    }

    // ---- epilogue: direct fragment stores (R5-proven clean) ----
    const int crow0 = (lane >> 4) * 4;
    #pragma unroll
    for (int m = 0; m < 4; ++m) {
        #pragma unroll
        for (int n = 0; n < 4; ++n) {
            #pragma unroll
            for (int r = 0; r < 4; ++r) {
                const int li = wm + m * 16 + crow0 + r;
                const int lj = wn + n * 16 + fr;
                float v = acc[m][n][r];
                if (MASKED) {
                    if (i0 + li != j0 + lj) v *= rowf[li] * colf[lj];
                }
                const size_t off = (size_t)(i0 + li) * N + j0 + lj;
                if (OMODE == 0) {
                    Cf[off] = v;
                } else {
                    u16 h = bf16_rne(v);
                    Cs[off]      = h;
                    Cs[NN + off] = bf16_rne(v - bf16_f(h));
                }
            }
        }
    }
    #undef STAGE
    #undef COMPUTE
}

// ---------------------------------------------------------------------------
// Schedule (park-free slot plan, lifetime-verified — R11):
//   slots: O1=Arec, O2=R, O3=D (d_out); W1=ws[0:16M), W2=ws[16M:32M)
//   1. A2 = split(A)                 -> W2u   [dies after G1]
//   2. RT = build_right (R^T fp32)   -> O3    [dies after split_rt]
//   3. split_rt: R2 -> O1u, RT2 -> W1u, R fp32 -> O2
//   4. G1: Ts  = split(R2 ⊛ A2^T)    -> O3u   [RT dead]
//   5. G2: D2  = split(mask(Ts ⊛ R2^T)) -> W2u [A2 dead]
//   6. G3: T2s = split(RT2 ⊛ D2^T)   -> O3u   [Ts dead]
//   7. G4: Arec = T2s ⊛ RT2^T        -> O1 fp32 [R2 dead]
//   8. unsplit: D fp32 = D2(W2u)     -> O3    [T2s, RT2 dead]
// ws requirement: 32 MB. No d2d copies.
// ---------------------------------------------------------------------------
extern "C" void kernel_launch(void* const* d_in, const int* in_sizes, int n_in,
                              void* d_out, int out_size, void* d_ws, size_t ws_size,
                              hipStream_t stream) {
    const float* A     = (const float*)d_in[0];
    const float* O_all = (const float*)d_in[1];
    const int*   sel   = (const int*)d_in[2];
    const int*   wav   = (const int*)d_in[3];
    const int    Lw    = in_sizes[3];

    float* O1 = (float*)d_out;          // Arec slot
    float* O2 = O1 + NN;                // R slot
    float* O3 = O1 + 2 * NN;            // D slot

    u16*   W1u = (u16*)d_ws;                                  // ws[0,16M)
    u16*   W2u = (u16*)((char*)d_ws + 2 * NN * sizeof(u16));  // ws[16M,32M)
    u16*   O1u = (u16*)O1;
    u16*   O3u = (u16*)O3;

    const int SGRID = (int)(NN / (256 * 8));

    split_plain_k<<<SGRID, 256, 0, stream>>>(A, W2u);                      // A2 -> W2
    build_right_k<<<N / 2, 64, 0, stream>>>(O_all, sel, O3);               // RT -> O3
    split_rt_k<<<(N / 64) * (N / 64), 256, 0, stream>>>(O3, O1u, W1u, O2); // R2->O1u, RT2->W1u, R->O2

    gemm_bf3<0, 1><<<256, 256, 0, stream>>>(O1u, W2u, nullptr, O3u, nullptr, 0); // G1: Ts  -> O3u
    gemm_bf3<1, 1><<<256, 256, 0, stream>>>(O3u, O1u, nullptr, W2u, wav, Lw);    // G2: D2  -> W2u
    gemm_bf3<0, 1><<<256, 256, 0, stream>>>(W1u, W2u, nullptr, O3u, nullptr, 0); // G3: T2s -> O3u
    gemm_bf3<0, 0><<<256, 256, 0, stream>>>(O3u, W1u, O1, nullptr, nullptr, 0);  // G4: Arec -> O1
    unsplit_k<<<SGRID, 256, 0, stream>>>(W2u, O3);                               // D fp32 -> O3
}

// Round 13
// 265.442 us; speedup vs baseline: 1.2873x; 1.0939x over previous
//
#include <hip/hip_runtime.h>

#define N 2048
#define LEV 256
#define KS 16

typedef __attribute__((ext_vector_type(8))) short bfx8;
typedef __attribute__((ext_vector_type(4))) float fx4;
typedef unsigned short u16;
typedef unsigned int u32;

static const size_t NN = (size_t)N * N;

__device__ inline u16 bf16_rne(float f) {
    u32 u = __builtin_bit_cast(u32, f);
    u32 r = (u + 0x7FFFu + ((u >> 16) & 1u)) >> 16;
    return (u16)r;
}
__device__ inline float bf16_f(u16 h) {
    u32 u = ((u32)h) << 16;
    return __builtin_bit_cast(float, u);
}

// async global->LDS, 16B per lane. LDS dest = wave-uniform base + lane*16.
#define GLDS16(gp, lp) __builtin_amdgcn_global_load_lds( \
    (const __attribute__((address_space(1))) void*)(uintptr_t)(gp), \
    (__attribute__((address_space(3))) void*)(u32)(uintptr_t)(lp), 16, 0, 0)

// sum over the 4 lanes of each quad (lane^1 then lane^2), VALU-only via DPP.
__device__ inline float qadd(float x) {
#if __has_builtin(__builtin_amdgcn_mov_dpp)
    int a = __builtin_amdgcn_mov_dpp(__builtin_bit_cast(int, x), 0xB1, 0xF, 0xF, true);
    float y = x + __builtin_bit_cast(float, a);
    int b = __builtin_amdgcn_mov_dpp(__builtin_bit_cast(int, y), 0x4E, 0xF, 0xF, true);
    return y + __builtin_bit_cast(float, b);
#else
    float y = x + __shfl_xor(x, 1);
    return y + __shfl_xor(y, 2);
#endif
}

// ---------------------------------------------------------------------------
// FUSED front: blocks [0,2048) build RT = (U_{L-1}...U_0)^T (one column per
// wave, 2-deep prefetch, R11-proven ~68us at 8 blocks/CU); blocks [2048,
// 2048+8192) stream-split A into bf16 hi/lo planes in the idle wave slots.
// ---------------------------------------------------------------------------
__global__ __launch_bounds__(64)
void front_k(const float* __restrict__ O_all, const int* __restrict__ sel,
             float* __restrict__ RT, const float* __restrict__ A,
             u16* __restrict__ a2h) {
    __shared__ float x[2048];
    const int lane = threadIdx.x;

    if (blockIdx.x >= 2048) {           // ---- A-split path ----
        u16* a2l = a2h + NN;
        size_t p = (((size_t)blockIdx.x - 2048) * 64 + lane) * 8;
        float4 v0 = *(const float4*)(A + p);
        float4 v1 = *(const float4*)(A + p + 4);
        float vv[8] = {v0.x, v0.y, v0.z, v0.w, v1.x, v1.y, v1.z, v1.w};
        bfx8 hs, ls;
        #pragma unroll
        for (int i = 0; i < 8; ++i) {
            u16 h = bf16_rne(vv[i]);
            hs[i] = (short)h;
            ls[i] = (short)bf16_rne(vv[i] - bf16_f(h));
        }
        *(bfx8*)(a2h + p) = hs;
        *(bfx8*)(a2l + p) = ls;
        return;
    }

    // ---- build-right path ----
    const int i    = lane >> 2;     // row 0..15
    const int kg   = lane & 3;      // k-quarter 0..3
    const int col  = blockIdx.x;

    const float4 z = make_float4(0.f, 0.f, 0.f, 0.f);
    #pragma unroll
    for (int q = 0; q < 8; ++q) *(float4*)&x[q * 256 + lane * 4] = z;
    if (lane == 0) x[col] = 1.0f;   // e_col; in-order DS, same wave

    const float* obase = O_all + i * KS + kg * 4;
    const int*   gbase = sel + kg * 4;

#define CMP(f, g, wv) { \
    float p = f.x * x[g.x] + f.y * x[g.y] + f.z * x[g.z] + f.w * x[g.w]; \
    p = qadd(p); \
    if (kg == 0) x[wv] = p; }

    float4 f0 = *(const float4*)(obase);
    int4   g0 = *(const int4*)(gbase);
    int    w0 = sel[i];
    float4 f1 = *(const float4*)(obase + 256);
    int4   g1 = *(const int4*)(gbase + KS);
    int    w1 = sel[KS + i];

    for (int l = 0; l < LEV; l += 2) {
        float4 f2, f3; int4 g2, g3; int w2, w3;
        if (l + 2 < LEV) {
            f2 = *(const float4*)(obase + (size_t)(l + 2) * 256);
            g2 = *(const int4*)(gbase + (l + 2) * KS);
            w2 = sel[(l + 2) * KS + i];
            f3 = *(const float4*)(obase + (size_t)(l + 3) * 256);
            g3 = *(const int4*)(gbase + (l + 3) * KS);
            w3 = sel[(l + 3) * KS + i];
        } else { f2 = f0; g2 = g0; w2 = w0; f3 = f1; g3 = g1; w3 = w1; }

        CMP(f0, g0, w0)
        CMP(f1, g1, w1)
        f0 = f2; g0 = g2; w0 = w2;
        f1 = f3; g1 = g3; w1 = w3;
    }
#undef CMP

    #pragma unroll
    for (int q = 0; q < 8; ++q)
        *(float4*)&RT[(size_t)col * N + q * 256 + lane * 4] =
            *(const float4*)&x[q * 256 + lane * 4];
}

// ---------------------------------------------------------------------------
// From RT (= R^T row-major): R2 = split(R), RT2 = split(RT), R fp32 row-major.
// ---------------------------------------------------------------------------
__global__ __launch_bounds__(256)
void split_rt_k(const float* __restrict__ RT, u16* __restrict__ r2h,
                u16* __restrict__ rth, float* __restrict__ Rrm) {
    __shared__ float t[64][65];
    u16* r2l = r2h + NN;
    u16* rtl = rth + NN;
    const int r0 = (blockIdx.x >> 5) * 64, c0 = (blockIdx.x & 31) * 64;
    #pragma unroll
    for (int i = 0; i < 16; ++i) {
        int q = i * 256 + threadIdx.x;
        int rr = q >> 6, cc = q & 63;
        t[rr][cc] = RT[(size_t)(r0 + rr) * N + c0 + cc];
    }
    __syncthreads();
    #pragma unroll
    for (int i = 0; i < 16; ++i) {
        int q = i * 256 + threadIdx.x;
        int rr = q >> 6, cc = q & 63;
        float v = t[rr][cc];                        // RT[r0+rr][c0+cc]
        u16 h = bf16_rne(v);
        size_t po = (size_t)(r0 + rr) * N + c0 + cc;
        rth[po] = h;                                // split(RT)
        rtl[po] = bf16_rne(v - bf16_f(h));
        float w = t[cc][rr];                        // = R[c0+rr][r0+cc]
        u16 h2 = bf16_rne(w);
        size_t pt = (size_t)(c0 + rr) * N + r0 + cc;
        r2h[pt] = h2;                               // split(R)
        r2l[pt] = bf16_rne(w - bf16_f(h2));
        Rrm[pt] = w;                                // R fp32 (output slot)
    }
}

// ---------------------------------------------------------------------------
// D fp32 = hi + lo
// ---------------------------------------------------------------------------
__global__ __launch_bounds__(256)
void unsplit_k(const u16* __restrict__ hi, float* __restrict__ dst) {
    const u16* lo = hi + NN;
    size_t p = ((size_t)blockIdx.x * 256 + threadIdx.x) * 8;
    bfx8 hs = *(const bfx8*)(hi + p);
    bfx8 ls = *(const bfx8*)(lo + p);
    float4 o0, o1;
    o0.x = bf16_f((u16)hs[0]) + bf16_f((u16)ls[0]);
    o0.y = bf16_f((u16)hs[1]) + bf16_f((u16)ls[1]);
    o0.z = bf16_f((u16)hs[2]) + bf16_f((u16)ls[2]);
    o0.w = bf16_f((u16)hs[3]) + bf16_f((u16)ls[3]);
    o1.x = bf16_f((u16)hs[4]) + bf16_f((u16)ls[4]);
    o1.y = bf16_f((u16)hs[5]) + bf16_f((u16)ls[5]);
    o1.z = bf16_f((u16)hs[6]) + bf16_f((u16)ls[6]);
    o1.w = bf16_f((u16)hs[7]) + bf16_f((u16)ls[7]);
    *(float4*)(dst + p)     = o0;
    *(float4*)(dst + p + 4) = o1;
}

// ---------------------------------------------------------------------------
// C = X * Y^T via 3-term bf16 split MFMA.
// NEW structure: 128x64 tile, BK=64, SINGLE-buffered (48 KB LDS) -> grid 512
// = 2 blocks/CU co-resident. While one block drains its stage barrier, the
// other's MFMAs run (m114 wave-level overlap — needs grid > #CU, unlike R10).
// Both-sides XOR swizzle; XCD super-tile swizzle (each XCD owns 4 4x4
// super-tiles of the 16x32 block grid, bijective).
// ---------------------------------------------------------------------------
template<int MASKED, int OMODE>
__global__ __launch_bounds__(256)
void gemm_bf3(const u16* __restrict__ Xp, const u16* __restrict__ Yp,
              float* __restrict__ Cf, u16* __restrict__ Cs,
              const int* __restrict__ wav, int Lw) {
    // planes: Xh[128*64] @0, Xl @16384, Yh[64*64] @32768, Yl @40960 (bytes)
    __shared__ __align__(16) u16 sm[24576];        // 48 KB single buffer
    __shared__ float rowf[128], colf[64];

    const int tid = threadIdx.x;
    // XCD super-tile swizzle: 512 blocks, 16x32 tile grid, 32 super-tiles
    // (4x4 blocks); XCD x owns super-tiles 4x..4x+3.
    const int xcd = blockIdx.x & 7, idx = blockIdx.x >> 3;   // idx 0..63
    const int sup = 4 * xcd + (idx >> 4);                    // 0..31
    const int wi4 = idx & 15;
    const int by = (sup >> 3) * 4 + (wi4 >> 2);              // 0..15
    const int bx = (sup & 7) * 4 + (wi4 & 3);                // 0..31
    const int i0 = by * 128, j0 = bx * 64;
    const int lane = tid & 63, w = tid >> 6;
    const int wm = (w >> 1) * 64, wn = (w & 1) * 32;
    const int fr = lane & 15;

    if (MASKED) {
        if (tid < 128) rowf[tid] = 1.0f;
        if (tid >= 128 && tid < 192) colf[tid - 128] = 1.0f;
        __syncthreads();
        for (int t = tid; t < Lw; t += 256) {
            int wv = wav[t];
            int dr = wv - i0; if (0 <= dr && dr < 128) rowf[dr] = 0.0f;
            int dc = wv - j0; if (0 <= dc && dc < 64)  colf[dc] = 0.0f;
        }
        // consumed only in epilogue (after main-loop barriers)
    }

    fx4 acc[4][2];
    #pragma unroll
    for (int m = 0; m < 4; ++m)
        #pragma unroll
        for (int n = 0; n < 2; ++n)
            acc[m][n] = (fx4)0.0f;

    const u16* Xh = Xp; const u16* Xl = Xp + NN;
    const u16* Yh = Yp; const u16* Yl = Yp + NN;

    const int rl   = lane >> 3;
    const int gcol = ((lane & 7) ^ rl) << 3;
    const int wq   = w * 1024;

    #define STAGE(kt) { \
        const int k0s = (kt) * 64; \
        char* lb0 = (char*)sm + wq; \
        _Pragma("unroll") \
        for (int q = 0; q < 4; ++q) { \
            const int row = q * 32 + w * 8 + rl; \
            const size_t xo = (size_t)(i0 + row) * N + k0s + gcol; \
            GLDS16(Xh + xo, lb0 + q * 4096); \
            GLDS16(Xl + xo, lb0 + 16384 + q * 4096); \
        } \
        _Pragma("unroll") \
        for (int q = 0; q < 2; ++q) { \
            const int row = q * 32 + w * 8 + rl; \
            const size_t yo = (size_t)(j0 + row) * N + k0s + gcol; \
            GLDS16(Yh + yo, lb0 + 32768 + q * 4096); \
            GLDS16(Yl + yo, lb0 + 40960 + q * 4096); \
        } }

    const int kq  = (lane >> 4) << 4;
    const int frx = (fr & 7) << 4;

    #define COMPUTE() { \
        const char* base = (const char*)sm; \
        _Pragma("unroll") \
        for (int s = 0; s < 2; ++s) { \
            const int cb = s * 64 + kq; \
            bfx8 ah[4], al[4]; \
            _Pragma("unroll") \
            for (int m = 0; m < 4; ++m) { \
                const int off = (wm + m * 16 + fr) * 128 + (cb ^ frx); \
                ah[m] = *(const bfx8*)(base + off); \
                al[m] = *(const bfx8*)(base + 16384 + off); \
            } \
            _Pragma("unroll") \
            for (int n = 0; n < 2; ++n) { \
                const int off = (wn + n * 16 + fr) * 128 + (cb ^ frx); \
                bfx8 bh = *(const bfx8*)(base + 32768 + off); \
                bfx8 bl = *(const bfx8*)(base + 40960 + off); \
                _Pragma("unroll") \
                for (int m = 0; m < 4; ++m) { \
                    acc[m][n] = __builtin_amdgcn_mfma_f32_16x16x32_bf16(ah[m], bh, acc[m][n], 0, 0, 0); \
                    acc[m][n] = __builtin_amdgcn_mfma_f32_16x16x32_bf16(ah[m], bl, acc[m][n], 0, 0, 0); \
                    acc[m][n] = __builtin_amdgcn_mfma_f32_16x16x32_bf16(al[m], bh, acc[m][n], 0, 0, 0); \
                } \
            } \
        } }

    constexpr int NT = N / 64;
    for (int kt = 0; kt < NT; ++kt) {
        STAGE(kt)
        __syncthreads();        // drains vmcnt -> tile ready
        COMPUTE()
        __syncthreads();        // reads done before next overwrite
    }

    // ---- epilogue: direct fragment stores (R5-proven clean) ----
    const int crow0 = (lane >> 4) * 4;
    #pragma unroll
    for (int m = 0; m < 4; ++m) {
        #pragma unroll
        for (int n = 0; n < 2; ++n) {
            #pragma unroll
            for (int r = 0; r < 4; ++r) {
                const int li = wm + m * 16 + crow0 + r;
                const int lj = wn + n * 16 + fr;
                float v = acc[m][n][r];
                if (MASKED) {
                    if (i0 + li != j0 + lj) v *= rowf[li] * colf[lj];
                }
                const size_t off = (size_t)(i0 + li) * N + j0 + lj;
                if (OMODE == 0) {
                    Cf[off] = v;
                } else {
                    u16 h = bf16_rne(v);
                    Cs[off]      = h;
                    Cs[NN + off] = bf16_rne(v - bf16_f(h));
                }
            }
        }
    }
    #undef STAGE
    #undef COMPUTE
}

// ---------------------------------------------------------------------------
// Schedule (park-free slot plan — R11):
//   slots: O1=Arec, O2=R, O3=D (d_out); W1=ws[0:16M), W2=ws[16M:32M)
//   1. front: RT -> O3; A2 = split(A) -> W2u      [fused launch]
//   2. split_rt: R2 -> O1u, RT2 -> W1u, R fp32 -> O2
//   3. G1: Ts  = split(R2 ⊛ A2^T)    -> O3u   [RT dead]
//   4. G2: D2  = split(mask(Ts ⊛ R2^T)) -> W2u [A2 dead]
//   5. G3: T2s = split(RT2 ⊛ D2^T)   -> O3u   [Ts dead]
//   6. G4: Arec = T2s ⊛ RT2^T        -> O1 fp32 [R2 dead]
//   7. unsplit: D fp32 = D2(W2u)     -> O3    [T2s, RT2 dead]
// ws requirement: 32 MB. No d2d copies.
// ---------------------------------------------------------------------------
extern "C" void kernel_launch(void* const* d_in, const int* in_sizes, int n_in,
                              void* d_out, int out_size, void* d_ws, size_t ws_size,
                              hipStream_t stream) {
    const float* A     = (const float*)d_in[0];
    const float* O_all = (const float*)d_in[1];
    const int*   sel   = (const int*)d_in[2];
    const int*   wav   = (const int*)d_in[3];
    const int    Lw    = in_sizes[3];

    float* O1 = (float*)d_out;          // Arec slot
    float* O2 = O1 + NN;                // R slot
    float* O3 = O1 + 2 * NN;            // D slot

    u16*   W1u = (u16*)d_ws;                                  // ws[0,16M)
    u16*   W2u = (u16*)((char*)d_ws + 2 * NN * sizeof(u16));  // ws[16M,32M)
    u16*   O1u = (u16*)O1;
    u16*   O3u = (u16*)O3;

    const int SGRID = (int)(NN / (256 * 8));

    front_k<<<2048 + (int)(NN / (64 * 8)), 64, 0, stream>>>(O_all, sel, O3, A, W2u);
    split_rt_k<<<(N / 64) * (N / 64), 256, 0, stream>>>(O3, O1u, W1u, O2); // R2->O1u, RT2->W1u, R->O2

    gemm_bf3<0, 1><<<512, 256, 0, stream>>>(O1u, W2u, nullptr, O3u, nullptr, 0); // G1: Ts  -> O3u
    gemm_bf3<1, 1><<<512, 256, 0, stream>>>(O3u, O1u, nullptr, W2u, wav, Lw);    // G2: D2  -> W2u
    gemm_bf3<0, 1><<<512, 256, 0, stream>>>(W1u, W2u, nullptr, O3u, nullptr, 0); // G3: T2s -> O3u
    gemm_bf3<0, 0><<<512, 256, 0, stream>>>(O3u, W1u, O1, nullptr, nullptr, 0);  // G4: Arec -> O1
    unsplit_k<<<SGRID, 256, 0, stream>>>(W2u, O3);                               // D fp32 -> O3
}